// Round 1
// baseline (651.265 us; speedup 1.0000x reference)
//
#include <hip/hip_runtime.h>
#include <hip/hip_bf16.h>

typedef __attribute__((ext_vector_type(4))) float f32x4;
typedef __attribute__((ext_vector_type(8))) short s16x8;
typedef unsigned short ushort_t;

// Sizes: B=4, H=W=64 -> N=4096, C=512, GROUPS=32 (cg=16)
#define N_DIM 4096
#define C_DIM 512

static __device__ __forceinline__ unsigned short f2bf(float f) {
    union { float f; unsigned u; } v; v.f = f;
    unsigned r = v.u + 0x7FFFu + ((v.u >> 16) & 1u);
    return (unsigned short)(r >> 16);
}

// ---------------- GroupNorm stats: one block per (b,g), reduce 4096*16 elems
__global__ void gn_stats_kernel(const float* __restrict__ x, float* __restrict__ stats) {
    int bg = blockIdx.x;
    int b = bg >> 5, g = bg & 31;
    const float* base = x + (size_t)b * (N_DIM * C_DIM) + g * 16;
    float sum = 0.f, ss = 0.f;
    for (int n = threadIdx.x; n < N_DIM; n += 256) {
        const float4* p = (const float4*)(base + (size_t)n * C_DIM);
        #pragma unroll
        for (int t = 0; t < 4; ++t) {
            float4 v = p[t];
            sum += v.x + v.y + v.z + v.w;
            ss  += v.x*v.x + v.y*v.y + v.z*v.z + v.w*v.w;
        }
    }
    #pragma unroll
    for (int o = 32; o > 0; o >>= 1) {
        sum += __shfl_down(sum, o);
        ss  += __shfl_down(ss, o);
    }
    __shared__ float red[8];
    int wid = threadIdx.x >> 6, lane = threadIdx.x & 63;
    if (lane == 0) { red[wid*2] = sum; red[wid*2+1] = ss; }
    __syncthreads();
    if (threadIdx.x == 0) {
        sum = red[0]+red[2]+red[4]+red[6];
        ss  = red[1]+red[3]+red[5]+red[7];
        float mean = sum * (1.f/65536.f);
        float var  = ss  * (1.f/65536.f) - mean*mean;
        stats[bg*2]   = mean;
        stats[bg*2+1] = rsqrtf(var + 1e-5f);
    }
}

// ---------------- normalize + gamma/beta + cast to bf16
__global__ void gn_norm_kernel(const float* __restrict__ x, const float* __restrict__ gamma,
                               const float* __restrict__ beta, const float* __restrict__ stats,
                               ushort_t* __restrict__ xn) {
    size_t i = ((size_t)blockIdx.x * 256 + threadIdx.x) * 4;
    int c = (int)(i & 511);
    int b = (int)(i >> 21);
    int bg = b*32 + (c >> 4);
    float mean = stats[bg*2], rstd = stats[bg*2+1];
    float4 v  = *(const float4*)(x + i);
    float4 ga = *(const float4*)(gamma + c);
    float4 be = *(const float4*)(beta + c);
    ushort4 o;
    o.x = f2bf((v.x - mean) * rstd * ga.x + be.x);
    o.y = f2bf((v.y - mean) * rstd * ga.y + be.y);
    o.z = f2bf((v.z - mean) * rstd * ga.z + be.z);
    o.w = f2bf((v.w - mean) * rstd * ga.w + be.w);
    *(ushort4*)(xn + i) = o;
}

// ---------------- weights: fp32 [Cin][Cout] -> bf16 transposed [Cout][Cin], 4 mats
__global__ void wconv_kernel(const float* __restrict__ wq, const float* __restrict__ wk,
                             const float* __restrict__ wv, const float* __restrict__ wp,
                             ushort_t* __restrict__ wt) {
    int idx = blockIdx.x * 256 + threadIdx.x;
    int m = idx >> 18;
    int r = idx & 262143;
    int ci = r >> 9, co = r & 511;
    const float* w = (m == 0) ? wq : (m == 1) ? wk : (m == 2) ? wv : wp;
    wt[(size_t)m * 262144 + (size_t)co * 512 + ci] = f2bf(w[(size_t)ci * 512 + co]);
}

// ---------------- QKV GEMM: xn[16384,512] @ Wt -> q,k (row-major, q pre-scaled), v (transposed per batch)
__global__ __launch_bounds__(256) void qkv_kernel(const ushort_t* __restrict__ xn, const ushort_t* __restrict__ wt,
                         const float* __restrict__ bq, const float* __restrict__ bk, const float* __restrict__ bv,
                         ushort_t* __restrict__ q, ushort_t* __restrict__ k, ushort_t* __restrict__ v) {
    int z = blockIdx.z;
    const ushort_t* W = wt + (size_t)z * 262144;
    const float* bias = (z == 0) ? bq : (z == 1) ? bk : bv;
    float scale = (z == 0) ? 0.04419417382415922f : 1.0f;  // 512^-0.5 folded into q
    int wid = threadIdx.x >> 6, lane = threadIdx.x & 63;
    int lr = lane & 15, lg = lane >> 4;
    int r0 = blockIdx.x * 64 + wid * 16;
    int c0 = blockIdx.y * 64;
    const ushort_t* arow = xn + (size_t)(r0 + lr) * 512 + lg * 8;
    f32x4 acc[4] = {};
    for (int k0 = 0; k0 < 512; k0 += 32) {
        s16x8 af = *(const s16x8*)(arow + k0);
        #pragma unroll
        for (int ct = 0; ct < 4; ++ct) {
            s16x8 bf = *(const s16x8*)(W + (size_t)(c0 + ct*16 + lr) * 512 + k0 + lg * 8);
            acc[ct] = __builtin_amdgcn_mfma_f32_16x16x32_bf16(af, bf, acc[ct], 0, 0, 0);
        }
    }
    if (z < 2) {
        ushort_t* out = (z == 0) ? q : k;
        #pragma unroll
        for (int ct = 0; ct < 4; ++ct) {
            int cg = c0 + ct*16 + lr;
            float bb = bias[cg];
            #pragma unroll
            for (int r2 = 0; r2 < 4; ++r2) {
                int row = r0 + lg*4 + r2;
                out[(size_t)row * 512 + cg] = f2bf((acc[ct][r2] + bb) * scale);
            }
        }
    } else {
        #pragma unroll
        for (int ct = 0; ct < 4; ++ct) {
            int cg = c0 + ct*16 + lr;
            float bb = bias[cg];
            int row = r0 + lg*4;
            int batch = row >> 12, j = row & 4095;
            ushort4 o;
            o.x = f2bf(acc[ct][0] + bb);
            o.y = f2bf(acc[ct][1] + bb);
            o.z = f2bf(acc[ct][2] + bb);
            o.w = f2bf(acc[ct][3] + bb);
            *(ushort4*)(v + (size_t)batch * (512*4096) + (size_t)cg * 4096 + j) = o;
        }
    }
}

// ---------------- flash attention: swapped QK^T (S^T via mfma(K,Q)), online softmax,
// P repacked cross-lane to K=32 B-fragment, PV uses V^T staged in LDS.
__global__ __launch_bounds__(256, 1) void attn_kernel(const ushort_t* __restrict__ q, const ushort_t* __restrict__ k,
                          const ushort_t* __restrict__ vt, ushort_t* __restrict__ O) {
    __shared__ ushort_t klds[32 * 512];   // [j 0..31][c 0..511], 16B-granule XOR swizzle by row
    __shared__ ushort_t vlds[512 * 32];   // [c 0..511][j 0..31], 16B-granule XOR swizzle by (c>>1)&3
    int tid = threadIdx.x;
    int wid = tid >> 6, lane = tid & 63;
    int lr = lane & 15, lg = lane >> 4;
    int batch = blockIdx.y;
    int i0 = blockIdx.x * 64 + wid * 16;
    const ushort_t* qb = q  + (size_t)batch * (4096*512);
    const ushort_t* kb = k  + (size_t)batch * (4096*512);
    const ushort_t* vb = vt + (size_t)batch * (512*4096);

    // Q fragments (B-operand of mfma(K,Q)): lane holds q[(i0+lr)][t*32 + lg*8 + 0..7]
    s16x8 qf[16];
    const ushort_t* qrow = qb + (size_t)(i0 + lr) * 512 + lg * 8;
    #pragma unroll
    for (int t = 0; t < 16; ++t) qf[t] = *(const s16x8*)(qrow + t * 32);

    f32x4 oacc[32];
    #pragma unroll
    for (int t = 0; t < 32; ++t) oacc[t] = (f32x4){0.f,0.f,0.f,0.f};
    float m = -1e30f, s = 0.f;

    for (int j0 = 0; j0 < 4096; j0 += 32) {
        __syncthreads();
        // stage K tile rows j0..j0+31 (32KB)
        #pragma unroll
        for (int p = 0; p < 8; ++p) {
            int gi = p * 256 + tid;
            int row = gi >> 6, slot = gi & 63;
            s16x8 val = *(const s16x8*)(kb + (size_t)(j0 + row) * 512 + slot * 8);
            *(s16x8*)(klds + row * 512 + ((slot * 8) ^ ((row & 7) * 8))) = val;
        }
        // stage V^T tile cols j0..j0+31 (32KB)
        #pragma unroll
        for (int p = 0; p < 8; ++p) {
            int gi = p * 256 + tid;
            int c = gi >> 2, slot = gi & 3;
            s16x8 val = *(const s16x8*)(vb + (size_t)c * 4096 + j0 + slot * 8);
            *(s16x8*)(vlds + c * 32 + ((slot ^ ((c >> 1) & 3)) * 8)) = val;
        }
        __syncthreads();

        // S^T = K_tile . Q^T : two 16x16 j-tiles, 2 chains each for ILP
        f32x4 sa = {0,0,0,0}, sb = {0,0,0,0}, sc2 = {0,0,0,0}, sd = {0,0,0,0};
        #pragma unroll
        for (int t = 0; t < 16; t += 2) {
            s16x8 k0f = *(const s16x8*)(klds + lr*512        + ((t*32 + lg*8)      ^ ((lr&7)*8)));
            s16x8 k1f = *(const s16x8*)(klds + lr*512        + (((t+1)*32 + lg*8)  ^ ((lr&7)*8)));
            s16x8 k2f = *(const s16x8*)(klds + (16+lr)*512   + ((t*32 + lg*8)      ^ ((lr&7)*8)));
            s16x8 k3f = *(const s16x8*)(klds + (16+lr)*512   + (((t+1)*32 + lg*8)  ^ ((lr&7)*8)));
            sa  = __builtin_amdgcn_mfma_f32_16x16x32_bf16(k0f, qf[t],   sa,  0,0,0);
            sb  = __builtin_amdgcn_mfma_f32_16x16x32_bf16(k1f, qf[t+1], sb,  0,0,0);
            sc2 = __builtin_amdgcn_mfma_f32_16x16x32_bf16(k2f, qf[t],   sc2, 0,0,0);
            sd  = __builtin_amdgcn_mfma_f32_16x16x32_bf16(k3f, qf[t+1], sd,  0,0,0);
        }
        f32x4 s1 = sa + sb;   // S^T[j0+4*lg+r][i0+lr]
        f32x4 s2 = sc2 + sd;  // S^T[j0+16+4*lg+r][i0+lr]

        // online softmax (per q-row i = lr column; reduce over lanes lg=0..3)
        float tm = fmaxf(fmaxf(fmaxf(s1[0], s1[1]), fmaxf(s1[2], s1[3])),
                         fmaxf(fmaxf(s2[0], s2[1]), fmaxf(s2[2], s2[3])));
        tm = fmaxf(tm, __shfl_xor(tm, 16));
        tm = fmaxf(tm, __shfl_xor(tm, 32));
        if (__any(tm > m)) {
            float mnew = fmaxf(m, tm);
            float resc = __expf(m - mnew);
            #pragma unroll
            for (int t = 0; t < 32; ++t) oacc[t] *= resc;
            s *= resc;
            m = mnew;
        }
        f32x4 p1, p2;
        #pragma unroll
        for (int r2 = 0; r2 < 4; ++r2) { p1[r2] = __expf(s1[r2] - m); p2[r2] = __expf(s2[r2] - m); }
        float ts = p1[0]+p1[1]+p1[2]+p1[3] + p2[0]+p2[1]+p2[2]+p2[3];
        ts += __shfl_xor(ts, 16);
        ts += __shfl_xor(ts, 32);
        s += ts;

        // pack P to bf16 pairs; cross-lane gather into K=32 B-fragment layout:
        // target lane (lr,g) reg r needs P^T[j0 + 8g + r][i0+lr]
        unsigned w0 = (unsigned)f2bf(p1[0]) | ((unsigned)f2bf(p1[1]) << 16);
        unsigned w1 = (unsigned)f2bf(p1[2]) | ((unsigned)f2bf(p1[3]) << 16);
        unsigned w2 = (unsigned)f2bf(p2[0]) | ((unsigned)f2bf(p2[1]) << 16);
        unsigned w3 = (unsigned)f2bf(p2[2]) | ((unsigned)f2bf(p2[3]) << 16);
        int s0l = lr + ((lg & 1) << 5);
        int s1l = s0l + 16;
        unsigned a0 = (unsigned)__shfl((int)w0, s0l), a1 = (unsigned)__shfl((int)w1, s0l);
        unsigned b0 = (unsigned)__shfl((int)w0, s1l), b1 = (unsigned)__shfl((int)w1, s1l);
        unsigned c0w = (unsigned)__shfl((int)w2, s0l), c1 = (unsigned)__shfl((int)w3, s0l);
        unsigned d0 = (unsigned)__shfl((int)w2, s1l), d1 = (unsigned)__shfl((int)w3, s1l);
        bool hi = (lg >= 2);
        union { unsigned u[4]; s16x8 v8; } pu;
        pu.u[0] = hi ? c0w : a0;
        pu.u[1] = hi ? c1  : a1;
        pu.u[2] = hi ? d0  : b0;
        pu.u[3] = hi ? d1  : b1;
        s16x8 pf = pu.v8;

        // O^T += V^T_tile . P^T   (A: V^T[c][j], 16B contiguous from vlds)
        #pragma unroll
        for (int ct = 0; ct < 32; ++ct) {
            int c = ct * 16 + lr;
            s16x8 vf = *(const s16x8*)(vlds + c * 32 + ((lg ^ ((c >> 1) & 3)) * 8));
            oacc[ct] = __builtin_amdgcn_mfma_f32_16x16x32_bf16(vf, pf, oacc[ct], 0,0,0);
        }
    }
    float inv = 1.f / s;
    ushort_t* orow = O + (size_t)batch * (4096*512) + (size_t)(i0 + lr) * 512 + lg * 4;
    #pragma unroll
    for (int ct = 0; ct < 32; ++ct) {
        ushort4 o;
        o.x = f2bf(oacc[ct][0] * inv);
        o.y = f2bf(oacc[ct][1] * inv);
        o.z = f2bf(oacc[ct][2] * inv);
        o.w = f2bf(oacc[ct][3] * inv);
        *(ushort4*)(orow + ct * 16) = o;
    }
}

// ---------------- final projection + bias + residual (fp32 out)
__global__ __launch_bounds__(256) void proj_kernel(const ushort_t* __restrict__ O, const ushort_t* __restrict__ wt,
                          const float* __restrict__ bp, const float* __restrict__ x, float* __restrict__ out) {
    int wid = threadIdx.x >> 6, lane = threadIdx.x & 63;
    int lr = lane & 15, lg = lane >> 4;
    int r0 = blockIdx.x * 64 + wid * 16;
    int c0 = blockIdx.y * 64;
    const ushort_t* W = wt + (size_t)3 * 262144;
    const ushort_t* arow = O + (size_t)(r0 + lr) * 512 + lg * 8;
    f32x4 acc[4] = {};
    for (int k0 = 0; k0 < 512; k0 += 32) {
        s16x8 af = *(const s16x8*)(arow + k0);
        #pragma unroll
        for (int ct = 0; ct < 4; ++ct) {
            s16x8 bf = *(const s16x8*)(W + (size_t)(c0 + ct*16 + lr) * 512 + k0 + lg * 8);
            acc[ct] = __builtin_amdgcn_mfma_f32_16x16x32_bf16(af, bf, acc[ct], 0, 0, 0);
        }
    }
    #pragma unroll
    for (int ct = 0; ct < 4; ++ct) {
        int cg = c0 + ct*16 + lr;
        float bb = bp[cg];
        #pragma unroll
        for (int r2 = 0; r2 < 4; ++r2) {
            size_t idx = (size_t)(r0 + lg*4 + r2) * 512 + cg;
            out[idx] = acc[ct][r2] + bb + x[idx];
        }
    }
}

extern "C" void kernel_launch(void* const* d_in, const int* in_sizes, int n_in,
                              void* d_out, int out_size, void* d_ws, size_t ws_size,
                              hipStream_t stream) {
    (void)in_sizes; (void)n_in; (void)out_size; (void)ws_size;
    const float* x     = (const float*)d_in[0];
    const float* gamma = (const float*)d_in[1];
    const float* beta  = (const float*)d_in[2];
    const float* wq    = (const float*)d_in[3];
    const float* bq    = (const float*)d_in[4];
    const float* wk    = (const float*)d_in[5];
    const float* bk    = (const float*)d_in[6];
    const float* wv    = (const float*)d_in[7];
    const float* bv    = (const float*)d_in[8];
    const float* wp    = (const float*)d_in[9];
    const float* bp    = (const float*)d_in[10];
    float* out = (float*)d_out;

    char* ws = (char*)d_ws;
    ushort_t* wt   = (ushort_t*)(ws);                 // 2 MB  (4x 512x512 bf16, transposed)
    float*    stats= (float*)(ws + (2ull<<20));       // 1 KB
    ushort_t* xn   = (ushort_t*)(ws + (4ull<<20));    // 16 MB
    ushort_t* qb   = (ushort_t*)(ws + (20ull<<20));   // 16 MB (pre-scaled by C^-0.5)
    ushort_t* kb   = (ushort_t*)(ws + (36ull<<20));   // 16 MB
    ushort_t* vt   = (ushort_t*)(ws + (52ull<<20));   // 16 MB ([b][c][n] transposed)
    ushort_t* Ob   = (ushort_t*)(ws + (68ull<<20));   // 16 MB

    hipLaunchKernelGGL(wconv_kernel,    dim3(4096),       dim3(256), 0, stream, wq, wk, wv, wp, wt);
    hipLaunchKernelGGL(gn_stats_kernel, dim3(128),        dim3(256), 0, stream, x, stats);
    hipLaunchKernelGGL(gn_norm_kernel,  dim3(8192),       dim3(256), 0, stream, x, gamma, beta, stats, xn);
    hipLaunchKernelGGL(qkv_kernel,      dim3(256, 8, 3),  dim3(256), 0, stream, xn, wt, bq, bk, bv, qb, kb, vt);
    hipLaunchKernelGGL(attn_kernel,     dim3(64, 4),      dim3(256), 0, stream, qb, kb, vt, Ob);
    hipLaunchKernelGGL(proj_kernel,     dim3(256, 8),     dim3(256), 0, stream, Ob, wt, bp, x, out);
}